// Round 1
// baseline (6994.662 us; speedup 1.0000x reference)
//
#include <hip/hip_runtime.h>
#include <hip/hip_bf16.h>
#include <math.h>

// ---- problem constants ----
#define V    32000
#define E    512
#define NH   8
#define DH   64
#define NL   2
#define FF   2048
#define MAXLEN 24
#define S    48
#define B    8
#define TRANS 14
#define INIT 12      // TRANS - 2
#define LF   35      // INIT + MAXLEN - 1

__device__ inline float wsum(float v) {
#pragma unroll
  for (int off = 32; off; off >>= 1) v += __shfl_xor(v, off);
  return v;
}
__device__ inline float wmax(float v) {
#pragma unroll
  for (int off = 32; off; off >>= 1) v = fmaxf(v, __shfl_xor(v, off));
  return v;
}

// ---- embed initial target tokens: xbuf[pos*B+b] = emb[transform[1+pos][b]] + pe[pos] ----
__global__ void embed_init_k(const int* __restrict__ transform, const float* __restrict__ emb,
                             float* __restrict__ xbuf) {
  int t = blockIdx.x;          // 0..INIT*B-1, pos-major
  int pos = t >> 3, b = t & 7;
  int tok = transform[(1 + pos) * B + b];
  for (int d = threadIdx.x; d < E; d += blockDim.x) {
    double div = exp(-log(10000.0) * (double)(d & ~1) / (double)E);
    double ang = (double)pos * div;
    float pe = (d & 1) ? (float)cos(ang) : (float)sin(ang);
    xbuf[(size_t)t * E + d] = emb[(size_t)tok * E + d] + pe;
  }
}

// ---- generic fp32 GEMM: out[t,o] = act( sum_d x[t,d]*W[o,d] + bias[o] ) ----
// wave-per-output-feature; W row held in registers; x tile (8 tokens) staged in LDS.
// route 0: out0[t*nout+o]; route 1 (QKV): o<E->out0(q), <2E->out1(Kcache), else out2(Vcache), stride E;
// route 2 (cross KV): o<E->out0(K), else out1(V), stride E.
template <int K>
__global__ __launch_bounds__(256) void gemm_k(
    const float* __restrict__ x, const float* __restrict__ W, const float* __restrict__ bias,
    int ntok, int nout, int route, int relu,
    float* __restrict__ out0, float* __restrict__ out1, float* __restrict__ out2) {
  constexpr int K4 = K / 4;
  constexpr int J  = K / 256;           // float4's per lane
  __shared__ float4 xt[8][K4];
  const int tid = threadIdx.x;
  const int lane = tid & 63;
  const int o = blockIdx.x * 4 + (tid >> 6);

  float4 wr[J];
  if (o < nout) {
    const float4* Wr = (const float4*)(W + (size_t)o * K);
#pragma unroll
    for (int j = 0; j < J; ++j) wr[j] = Wr[lane + 64 * j];
  }

  const int ng = ntok >> 3;             // ntok is always a multiple of 8
  for (int g = 0; g < ng; ++g) {
    if (g) __syncthreads();
    const float4* xg = (const float4*)(x + (size_t)g * 8 * K);
    float4* xf = &xt[0][0];
    for (int i = tid; i < 8 * K4; i += 256) xf[i] = xg[i];
    __syncthreads();
    if (o < nout) {
      float acc[8] = {0, 0, 0, 0, 0, 0, 0, 0};
#pragma unroll
      for (int j = 0; j < J; ++j) {
        float4 w = wr[j];
#pragma unroll
        for (int tt = 0; tt < 8; ++tt) {
          float4 xv = xt[tt][lane + 64 * j];
          acc[tt] += w.x * xv.x + w.y * xv.y + w.z * xv.z + w.w * xv.w;
        }
      }
#pragma unroll
      for (int tt = 0; tt < 8; ++tt) acc[tt] = wsum(acc[tt]);
      if (lane == 0) {
        float bo = bias[o];
#pragma unroll
        for (int tt = 0; tt < 8; ++tt) {
          float v = acc[tt] + bo;
          if (relu) v = fmaxf(v, 0.f);
          int t = g * 8 + tt;
          if (route == 0) {
            out0[(size_t)t * nout + o] = v;
          } else if (route == 1) {
            if (o < E) out0[(size_t)t * E + o] = v;
            else if (o < 2 * E) out1[(size_t)t * E + (o - E)] = v;
            else out2[(size_t)t * E + (o - 2 * E)] = v;
          } else {
            if (o < E) out0[(size_t)t * E + o] = v;
            else out1[(size_t)t * E + (o - E)] = v;
          }
        }
      }
    }
  }
}

// ---- attention: one wave per (query-pos, b, h); lane = head dim; nk <= 48 <= 64 ----
// q: [nq*B, E] (pos-major, starting at global pos p0). K/V caches: [*, B, E] pos-major from 0.
__global__ __launch_bounds__(256) void attn_k(
    const float* __restrict__ q, const float* __restrict__ Kc, const float* __restrict__ Vc,
    float* __restrict__ outp, int p0, int nq, int nk_fixed, int causal) {
  const int tid = threadIdx.x;
  const int lane = tid & 63;
  const int u = blockIdx.x * 4 + (tid >> 6);
  if (u >= nq * 64) return;
  const int qi = u >> 6;
  const int r = u & 63;
  const int b = r >> 3, h = r & 7;
  const int nk = causal ? (p0 + qi + 1) : nk_fixed;

  const size_t qoff = (size_t)(qi * B + b) * E + h * DH + lane;
  const float qv = q[qoff];

  float myscore = -INFINITY;
  for (int k = 0; k < nk; ++k) {
    float prod = qv * Kc[(size_t)(k * B + b) * E + h * DH + lane];
    prod = wsum(prod);
    if (lane == k) myscore = prod * 0.125f;   // 1/sqrt(DH)
  }
  float m = wmax(myscore);
  float p = (lane < nk) ? expf(myscore - m) : 0.f;
  float denom = wsum(p);
  float a = p / denom;

  float oacc = 0.f;
  for (int k = 0; k < nk; ++k) {
    float ak = __shfl(a, k);
    oacc = fmaf(ak, Vc[(size_t)(k * B + b) * E + h * DH + lane], oacc);
  }
  outp[qoff] = oacc;
}

// ---- residual add + LayerNorm: out[t] = LN(xa[t]+xb[t])*g + beta ; one wave per token ----
__global__ __launch_bounds__(256) void add_ln_k(
    const float* __restrict__ xa, const float* __restrict__ xb,
    const float* __restrict__ g, const float* __restrict__ beta,
    float* __restrict__ outp, int ntok) {
  const int tid = threadIdx.x, lane = tid & 63;
  const int t = blockIdx.x * 4 + (tid >> 6);
  if (t >= ntok) return;
  float v[8];
  float s = 0.f;
#pragma unroll
  for (int j = 0; j < 8; ++j) {
    int d = lane + 64 * j;
    v[j] = xa[(size_t)t * E + d] + xb[(size_t)t * E + d];
    s += v[j];
  }
  s = wsum(s);
  float mean = s * (1.f / 512.f);
  float d2 = 0.f;
#pragma unroll
  for (int j = 0; j < 8; ++j) { float dd = v[j] - mean; d2 += dd * dd; }
  d2 = wsum(d2);
  float inv = 1.f / sqrtf(d2 * (1.f / 512.f) + 1e-5f);
#pragma unroll
  for (int j = 0; j < 8; ++j) {
    int d = lane + 64 * j;
    outp[(size_t)t * E + d] = (v[j] - mean) * inv * g[d] + beta[d];
  }
}

// ---- per-batch argmax over 32000 logits (first-max tie-break) + re-embed at pos+1 ----
__global__ __launch_bounds__(256) void argmax_embed_k(
    const float* __restrict__ logits, const float* __restrict__ emb,
    float* __restrict__ xbuf, int pos) {
  __shared__ float sv[256];
  __shared__ int si[256];
  const int b = blockIdx.x, tid = threadIdx.x;
  const float* row = logits + (size_t)b * V;
  float bv = -INFINITY; int bi = 0x7fffffff;
  for (int i = tid; i < V; i += 256) {
    float v = row[i];
    if (v > bv || (v == bv && i < bi)) { bv = v; bi = i; }
  }
  sv[tid] = bv; si[tid] = bi;
  __syncthreads();
  for (int s = 128; s; s >>= 1) {
    if (tid < s) {
      float ov = sv[tid + s]; int oi = si[tid + s];
      if (ov > sv[tid] || (ov == sv[tid] && oi < si[tid])) { sv[tid] = ov; si[tid] = oi; }
    }
    __syncthreads();
  }
  const int tok = si[0];
  const size_t dst = ((size_t)(pos + 1) * B + b) * E;
  for (int d = tid; d < E; d += 256) {
    // pe[0]: sin(0)=0 on even dims, cos(0)=1 on odd dims
    xbuf[dst + d] = emb[(size_t)tok * E + d] + ((d & 1) ? 1.0f : 0.0f);
  }
}

extern "C" void kernel_launch(void* const* d_in, const int* in_sizes, int n_in,
                              void* d_out, int out_size, void* d_ws, size_t ws_size,
                              hipStream_t stream) {
  const float* enc       = (const float*)d_in[0];   // [S,B,E]
  const int*   transform = (const int*)d_in[1];     // [TRANS,B]
  const float* emb       = (const float*)d_in[3];   // [V,E]
  const float* sa_w  = (const float*)d_in[4];
  const float* sa_b  = (const float*)d_in[5];
  const float* sa_ow = (const float*)d_in[6];
  const float* sa_ob = (const float*)d_in[7];
  const float* ca_w  = (const float*)d_in[8];
  const float* ca_b  = (const float*)d_in[9];
  const float* ca_ow = (const float*)d_in[10];
  const float* ca_ob = (const float*)d_in[11];
  const float* ff1_w = (const float*)d_in[12];
  const float* ff1_b = (const float*)d_in[13];
  const float* ff2_w = (const float*)d_in[14];
  const float* ff2_b = (const float*)d_in[15];
  const float* ln_g  = (const float*)d_in[16];
  const float* ln_b  = (const float*)d_in[17];
  const float* out_w = (const float*)d_in[18];
  const float* out_b = (const float*)d_in[19];
  float* out = (float*)d_out;

  // workspace layout (floats)
  const size_t SELF_SZ  = (size_t)LF * B * E;   // 143360
  const size_t CROSS_SZ = (size_t)S * B * E;    // 196608
  float* ws     = (float*)d_ws;
  float* xbuf   = ws;
  float* kself  = xbuf + SELF_SZ;
  float* vself  = kself + NL * SELF_SZ;
  float* kcross = vself + NL * SELF_SZ;
  float* vcross = kcross + NL * CROSS_SZ;
  float* act0   = vcross + NL * CROSS_SZ;       // [96,E]
  float* act1   = act0 + 96 * E;
  float* act2   = act1 + 96 * E;
  float* act3   = act2 + 96 * E;
  float* ffb    = act3 + 96 * E;                // [96,FF]

  // 1) initial embeddings (positions 0..11)
  embed_init_k<<<INIT * B, 128, 0, stream>>>(transform, emb, xbuf);

  // 2) cross-attn K/V caches (once per layer): enc(384 tok) x ca_w rows [E..3E)
  for (int l = 0; l < NL; ++l) {
    gemm_k<E><<<(2 * E) / 4, 256, 0, stream>>>(
        enc, ca_w + ((size_t)l * 3 * E + E) * E, ca_b + (size_t)l * 3 * E + E,
        S * B, 2 * E, 2, 0, kcross + l * CROSS_SZ, vcross + l * CROSS_SZ, nullptr);
  }

  // decode positions [p0, p0+nq): 2 decoder layers + logits rows
  auto decode = [&](int p0, int nq) {
    const int ntok = nq * B;
    const float* xin = xbuf + (size_t)p0 * B * E;
    for (int l = 0; l < NL; ++l) {
      const float* x = (l == 0) ? xin : act0;
      // self-attn QKV (writes K,V straight into cache at position p0)
      gemm_k<E><<<(3 * E) / 4, 256, 0, stream>>>(
          x, sa_w + (size_t)l * 3 * E * E, sa_b + (size_t)l * 3 * E, ntok, 3 * E, 1, 0,
          act1, kself + l * SELF_SZ + (size_t)p0 * B * E, vself + l * SELF_SZ + (size_t)p0 * B * E);
      attn_k<<<nq * 16, 256, 0, stream>>>(act1, kself + l * SELF_SZ, vself + l * SELF_SZ,
                                          act2, p0, nq, 0, 1);
      gemm_k<E><<<E / 4, 256, 0, stream>>>(
          act2, sa_ow + (size_t)l * E * E, sa_ob + (size_t)l * E, ntok, E, 0, 0, act3, nullptr, nullptr);
      add_ln_k<<<(ntok + 3) / 4, 256, 0, stream>>>(
          x, act3, ln_g + (size_t)l * 3 * E, ln_b + (size_t)l * 3 * E, act0, ntok);
      // cross-attn (Q proj only; K/V cached)
      gemm_k<E><<<E / 4, 256, 0, stream>>>(
          act0, ca_w + (size_t)l * 3 * E * E, ca_b + (size_t)l * 3 * E, ntok, E, 0, 0, act1, nullptr, nullptr);
      attn_k<<<nq * 16, 256, 0, stream>>>(act1, kcross + l * CROSS_SZ, vcross + l * CROSS_SZ,
                                          act2, p0, nq, S, 0);
      gemm_k<E><<<E / 4, 256, 0, stream>>>(
          act2, ca_ow + (size_t)l * E * E, ca_ob + (size_t)l * E, ntok, E, 0, 0, act3, nullptr, nullptr);
      add_ln_k<<<(ntok + 3) / 4, 256, 0, stream>>>(
          act0, act3, ln_g + (size_t)l * 3 * E + E, ln_b + (size_t)l * 3 * E + E, act0, ntok);
      // FFN
      gemm_k<E><<<FF / 4, 256, 0, stream>>>(
          act0, ff1_w + (size_t)l * FF * E, ff1_b + (size_t)l * FF, ntok, FF, 0, 1, ffb, nullptr, nullptr);
      gemm_k<FF><<<E / 4, 256, 0, stream>>>(
          ffb, ff2_w + (size_t)l * E * FF, ff2_b + (size_t)l * E, ntok, E, 0, 0, act3, nullptr, nullptr);
      add_ln_k<<<(ntok + 3) / 4, 256, 0, stream>>>(
          act0, act3, ln_g + (size_t)l * 3 * E + 2 * E, ln_b + (size_t)l * 3 * E + 2 * E, act0, ntok);
    }
    // output logits for these positions (also the final answer rows)
    gemm_k<E><<<V / 4, 256, 0, stream>>>(
        act0, out_w, out_b, ntok, V, 0, 0, out + (size_t)p0 * B * V, nullptr, nullptr);
  };

  // 3) prefill positions 0..11 (logits rows 0..11)
  decode(0, INIT);

  // 4) 23 autoregressive steps: argmax of row (11+i) -> embed at (12+i) -> decode pos (12+i)
  for (int i = 0; i < MAXLEN - 1; ++i) {
    const int pos = INIT - 1 + i;
    argmax_embed_k<<<B, 256, 0, stream>>>(out + (size_t)pos * B * V, emb, xbuf, pos);
    decode(pos + 1, 1);
  }
}